// Round 12
// baseline (45.209 us; speedup 1.0000x reference)
//
#include <hip/hip_runtime.h>

// Acrobot GN step, fused bf16-MFMA — BARRIER-FREE self-contained-wave design.
// Each wave owns a 16-row strip and computes ALL 128 features for it:
//   G1: e1 = relu(A1 @ in32)        8 MFMA, B built in regs, A1 from aLDS (broadcast)
//   G2: e2 = relu(A2 @ e1 + be2)    32 MFMA, A2 streamed from swizzled 32KB LDS table
//   G3: hdd = relu(A3 @ [e2[r^1]; sender,1])  32+8 MFMA, A3 resident in 128 AGPRs
//   G4: delta = Wn2^T @ hdd + bn2   f32 dot + shfl_xor g-reduce, direct store
// Aggregation row^1 stays inside the 16-row strip -> all LDS traffic is wave-private
// -> in-order LDS per wave gives correctness with ZERO s_barrier in the loop.
// R11 post-mortem: TLP/domain scaling saturated (~6%/step); the barrier convoy was
// the wall. This removes it structurally. 2 waves/SIMD, 2 WGs/CU, grid 512.

typedef __attribute__((ext_vector_type(8))) short bf16x8;
typedef __attribute__((ext_vector_type(4))) float f32x4;

union U4B { uint4 u; bf16x8 b; };

__device__ __forceinline__ unsigned short f2bf(float f) {
  union { float f; unsigned u; } v; v.f = f;
  return (unsigned short)((v.u + 0x7FFFu + ((v.u >> 16) & 1u)) >> 16);  // RNE
}

__device__ __forceinline__ unsigned cvtpk(float lo, float hi) {
  unsigned r;
  asm("v_cvt_pk_bf16_f32 %0, %1, %2" : "=v"(r) : "v"(lo), "v"(hi));
  return r;
}

// ---------------- weight prep: bf16 A-operand images in ws (unchanged from R11) ----
// shorts: A1c [128j][8k] @0 ; A3e [128j][8k] @1024 ; wn2 cols f32[2][128] @2048 (1KB);
//         A2 [128j][128k] @4096 ; A3 main [128j][128k] @20480. 36864 shorts = 73728 B.
__global__ void gn_prep(const float* __restrict__ We1, const float* __restrict__ be1,
                        const float* __restrict__ We2, const float* __restrict__ Wn1,
                        const float* __restrict__ bn1, const float* __restrict__ Wn2,
                        unsigned short* __restrict__ wsA) {
  int t = blockIdx.x * 256 + threadIdx.x;
  if (t < 1024) {                       // A1 compact: k<7 -> We1 rows 10..16 ; k==7 -> be1
    int j = t >> 3, k = t & 7;
    wsA[t] = f2bf((k < 7) ? We1[(10 + k) * 128 + j] : be1[j]);
  } else if (t < 2048) {                // A3ext compact: c0=Wn1r10, c1=Wn1r11, c2=bn1
    int t2 = t - 1024; int j = t2 >> 3, c = t2 & 7;
    float v = (c == 0) ? Wn1[10 * 128 + j] : (c == 1) ? Wn1[11 * 128 + j]
            : (c == 2) ? bn1[j] : 0.0f;
    wsA[t] = f2bf(v);
  } else if (t < 2304) {                // Wn2 columns, f32: [c][j]
    int f = t - 2048; int c = f >> 7, j = f & 127;
    ((float*)(wsA + 2048))[f] = Wn2[j * 2 + c];
  } else if (t >= 4096 && t < 20480) {  // A2 = We2^T
    int t2 = t - 4096; int j = t2 >> 7, k = t2 & 127;
    wsA[t] = f2bf(We2[k * 128 + j]);
  } else if (t >= 20480 && t < 36864) { // A3 main = Wn1[12:140]^T
    int t2 = t - 20480; int j = t2 >> 7, k = t2 & 127;
    wsA[t] = f2bf(Wn1[(12 + k) * 128 + j]);
  }
}

// ---------------- main fused kernel ----------------
#define WTILES 16384  // 262144 rows / 16 rows per wave-tile
#define NWAVES 2048   // grid 512 x 4 waves; 8 tiles per wave

__global__ __launch_bounds__(256) __attribute__((amdgpu_waves_per_eu(2, 2)))
void gn_main(
    const float* __restrict__ x, const float* __restrict__ u,
    const float* __restrict__ nmean, const float* __restrict__ nstd,
    const float* __restrict__ emean, const float* __restrict__ estd,
    const float* __restrict__ be2, const float* __restrict__ bn2,
    const unsigned short* __restrict__ wsA,
    float* __restrict__ out)
{
  __shared__ __align__(16) unsigned short a2T[128 * 128];   // 32KB swizzled A2 table
  __shared__ __align__(16) unsigned short strips[4][2048];  // 16KB: per-wave 16x128 strip
  __shared__ __align__(16) unsigned short aLDS[2560];       // 5KB: A1c|A3e|wn2cols

  const int tid  = threadIdx.x;
  const int lane = tid & 63;
  const int wid  = tid >> 6;     // wave 0..3, each fully independent after init
  const int c15  = lane & 15;
  const int g    = lane >> 4;    // 0..3
  const int sw15 = (c15 & 7) << 4;

  // ---- build swizzled A2 table + compact tables in LDS (one time) ----
  for (int t = tid; t < 2048; t += 256) {
    int j = t >> 4, c = t & 15;
    uint4 v = *(const uint4*)(wsA + 4096 + j * 128 + c * 8);
    *(uint4*)((char*)a2T + j * 256 + ((c * 16) ^ ((j & 7) << 4))) = v;
  }
  for (int t = tid; t < 1280; t += 256)
    ((unsigned*)aLDS)[t] = ((const unsigned*)wsA)[t];

  // ---- resident A3 fragments: full feature dim, 128 AGPRs ----
  bf16x8 A3f[8][4];
  #pragma unroll
  for (int m = 0; m < 8; ++m)
    #pragma unroll
    for (int kk = 0; kk < 4; ++kk)
      A3f[m][kk] = *(const bf16x8*)(wsA + 20480 + (m * 16 + c15) * 128 + kk * 32 + g * 8);

  const float nm0 = nmean[0], nm1 = nmean[1];
  const float is0 = 1.0f / nstd[0], is1 = 1.0f / nstd[1];
  const float em0 = emean[0], ie0 = 1.0f / estd[0];
  const float cea1 = (0.0f - emean[1]) / estd[1];
  const float cea2 = (0.0f - emean[2]) / estd[2];
  const float bn20 = bn2[0], bn21 = bn2[1];
  const unsigned cpkw = cvtpk(cea2, 1.0f);   // B dword3: [cea2, 1.0]

  unsigned short* strip = strips[wid];

  // ---- prefetch first tile's x/u ----
  float4 xv; float uv;
  if (g == 0) {
    int b = (blockIdx.x * 4 + wid) * 8 + (c15 >> 1);
    xv = *(const float4*)(x + b * 4);
    uv = u[b];
  }
  __syncthreads();   // tables ready — the ONLY barrier

  for (int wt = blockIdx.x * 4 + wid; wt < WTILES; wt += NWAVES) {
    const int rowbase = wt * 16;

    // opaque LDS offset: stop LICM from hoisting loop-invariant table reads into regs
    unsigned aoff = 0;
    asm volatile("" : "+v"(aoff));
    const char* aB  = (const char*)aLDS + aoff;
    const char* a2B = (const char*)a2T + aoff;
    const float* be2T = be2;
    asm volatile("" : "+s"(be2T));

    // ---------- build G1 B-operand in registers ----------
    unsigned pks = 0;
    bf16x8 Bv;
    {
      uint4 bu = (uint4){0u, 0u, 0u, 0u};
      if (g == 0) {                     // only k=0..7 nonzero; g==0 lanes hold them
        float a0 = (xv.x - nm0) * is0;  // node0 theta
        float a1 = (xv.z - nm1) * is1;  // node0 v
        float b0 = (xv.y - nm0) * is0;  // node1 theta
        float b1 = (xv.w - nm1) * is1;  // node1 v
        bool  e  = (c15 & 1);           // row parity = edge index
        float s0 = e ? b0 : a0, s1 = e ? b1 : a1;   // sender  feats
        float r0 = e ? a0 : b0, r1 = e ? a1 : b1;   // receiver feats
        float ea0 = (uv - em0) * ie0;
        bu.x = cvtpk(s0, s1);
        bu.y = cvtpk(r0, r1);
        bu.z = cvtpk(ea0, cea1);
        bu.w = cpkw;
      }
      pks = bu.x;                       // sender feats, reused as G3 node feats
      U4B t; t.u = bu; Bv = t.b;
    }

    // ---------- prefetch next tile's x/u ----------
    {
      int nt = wt + NWAVES;
      if (nt < WTILES && g == 0) {
        int b = nt * 8 + (c15 >> 1);
        xv = *(const float4*)(x + b * 4);
        uv = u[b];
      }
    }

    // ---------- G1: e1 = relu(A1 @ in32) -> strip (streamed per m) ----------
    #pragma unroll
    for (int m = 0; m < 8; ++m) {
      U4B ta; ta.u = *(const uint4*)(aB + (m * 16 + c15) * 16);   // A1 frag (broadcast)
      f32x4 a = (f32x4){0.f, 0.f, 0.f, 0.f};
      a = __builtin_amdgcn_mfma_f32_16x16x32_bf16(ta.b, Bv, a, 0, 0, 0);
      uint2 pk;
      pk.x = cvtpk(fmaxf(a[0], 0.f), fmaxf(a[1], 0.f));
      pk.y = cvtpk(fmaxf(a[2], 0.f), fmaxf(a[3], 0.f));
      *(uint2*)((char*)strip + c15 * 256 + ((m * 32 + g * 8) ^ sw15)) = pk;
    }

    // ---------- G2: e2 = relu(A2 @ e1 + be2); A2 streamed from LDS table ----------
    f32x4 acc[8];
    #pragma unroll
    for (int m = 0; m < 8; ++m)
      acc[m] = *(const f32x4*)(be2T + m * 16 + g * 4);            // be2 as C-init
    #pragma unroll
    for (int kk = 0; kk < 4; ++kk) {
      bf16x8 B = *(const bf16x8*)((const char*)strip + c15 * 256 + ((kk * 64 + g * 16) ^ sw15));
      #pragma unroll
      for (int m = 0; m < 8; ++m) {
        int j = m * 16 + c15;
        U4B ta; ta.u = *(const uint4*)(a2B + j * 256 + ((kk * 64 + g * 16) ^ sw15));
        acc[m] = __builtin_amdgcn_mfma_f32_16x16x32_bf16(ta.b, B, acc[m], 0, 0, 0);
      }
    }
    #pragma unroll
    for (int m = 0; m < 8; ++m) {                                 // e2 over e1 (in-order LDS)
      uint2 pk;
      pk.x = cvtpk(fmaxf(acc[m][0], 0.f), fmaxf(acc[m][1], 0.f));
      pk.y = cvtpk(fmaxf(acc[m][2], 0.f), fmaxf(acc[m][3], 0.f));
      *(uint2*)((char*)strip + c15 * 256 + ((m * 32 + g * 8) ^ sw15)) = pk;
    }

    // ---------- G3: hdd = relu(A3 @ [e2[r^1]; sender,1]); A3 resident ----------
    #pragma unroll
    for (int m = 0; m < 8; ++m) acc[m] = (f32x4){0.f, 0.f, 0.f, 0.f};
    {
      int rsw = c15 ^ 1;                // aggregation = paired-row swap, inside strip
      int rb = rsw * 256, sw = (rsw & 7) << 4;
      #pragma unroll
      for (int kk = 0; kk < 4; ++kk) {
        bf16x8 B = *(const bf16x8*)((const char*)strip + rb + ((kk * 64 + g * 16) ^ sw));
        #pragma unroll
        for (int m = 0; m < 8; ++m)
          acc[m] = __builtin_amdgcn_mfma_f32_16x16x32_bf16(A3f[m][kk], B, acc[m], 0, 0, 0);
      }
      // K-chunk 4: node feats (= sender feats) + const-1 (bn1 column)
      uint4 b4u = (uint4){0u, 0u, 0u, 0u};
      if (g == 0) { b4u.x = pks; b4u.y = 0x00003F80u; }
      U4B t4; t4.u = b4u;
      #pragma unroll
      for (int m = 0; m < 8; ++m) {
        U4B ta; ta.u = *(const uint4*)(aB + 2048 + (m * 16 + c15) * 16);  // A3e (broadcast)
        acc[m] = __builtin_amdgcn_mfma_f32_16x16x32_bf16(ta.b, t4.b, acc[m], 0, 0, 0);
      }
    }

    // ---------- G4: delta = Wn2^T @ relu(hdd) + bn2; dot + g-reduce + store ----------
    {
      float p0 = 0.f, p1 = 0.f;
      #pragma unroll
      for (int m = 0; m < 8; ++m) {
        int jo = (m * 16 + g * 4) * 4;                 // byte offset into f32[128]
        f32x4 w0 = *(const f32x4*)(aB + 4096 + jo);    // Wn2 col0 (broadcast)
        f32x4 w1 = *(const f32x4*)(aB + 4608 + jo);    // Wn2 col1
        #pragma unroll
        for (int r = 0; r < 4; ++r) {
          float h = fmaxf(acc[m][r], 0.f);
          p0 += h * w0[r];
          p1 += h * w1[r];
        }
      }
      p0 += __shfl_xor(p0, 16, 64); p0 += __shfl_xor(p0, 32, 64);
      p1 += __shfl_xor(p1, 16, 64); p1 += __shfl_xor(p1, 32, 64);
      if (g == 0) {                    // lane holds delta c0,c1 for row rowbase+c15
        int gr = rowbase + c15;
        int bidx = gr >> 1, k = gr & 1;
        out[bidx * 4 + k]     = x[bidx * 4 + k]     + p0 + bn20;
        out[bidx * 4 + k + 2] = x[bidx * 4 + k + 2] + p1 + bn21;
      }
    }
    // no barrier: strip reuse next iteration is same-wave, in-order LDS.
  }
}

extern "C" void kernel_launch(void* const* d_in, const int* in_sizes, int n_in,
                              void* d_out, int out_size, void* d_ws, size_t ws_size,
                              hipStream_t stream) {
  const float* x   = (const float*)d_in[0];
  const float* u   = (const float*)d_in[1];
  const float* nm  = (const float*)d_in[2];
  const float* ns  = (const float*)d_in[3];
  const float* em  = (const float*)d_in[4];
  const float* es  = (const float*)d_in[5];
  const float* We1 = (const float*)d_in[6];
  const float* be1 = (const float*)d_in[7];
  const float* We2 = (const float*)d_in[8];
  const float* be2 = (const float*)d_in[9];
  const float* Wn1 = (const float*)d_in[10];
  const float* bn1 = (const float*)d_in[11];
  const float* Wn2 = (const float*)d_in[12];
  const float* bn2 = (const float*)d_in[13];
  unsigned short* wsA = (unsigned short*)d_ws;   // needs 73728 bytes
  float* out = (float*)d_out;

  gn_prep<<<144, 256, 0, stream>>>(We1, be1, We2, Wn1, bn1, Wn2, wsA);
  gn_main<<<512, 256, 0, stream>>>(x, u, nm, ns, em, es, be2, bn2, wsA, out);
}

// Round 13
// 41.486 us; speedup vs baseline: 1.0897x; 1.0897x over previous
//
#include <hip/hip_runtime.h>

// Acrobot GN step — fully IN-REGISTER layer chaining (zero activation LDS, zero barriers
// in loop). Each wave owns a 16-row strip:
//   G1: e1 = relu(A1 @ in32)        8 MFMA, B built in regs
//   G2: e2 = relu(A2 @ e1 + be2)    32 MFMA, A2 streamed from swizzled 32KB LDS table,
//                                   e1 consumed IN-REGISTER (A2 image K-permuted by kperm)
//   G3: hdd = relu(A3 @ [e2[r^1]; sender,1])  40 MFMA, A3 resident (128 AGPR, K-permuted);
//                                   row^1 agg = __shfl_xor(.,1) on packed e2 (16 dwords)
//   G4: delta = Wn2^T @ hdd + bn2   f32 dot + shfl_xor g-reduce, direct store
//
// Why: C/D->B relayout only redistributes features among lanes {c15+16g}; permuting the
// next layer's weight-image K dim (kperm) makes the lane-local packed accumulator ALREADY
// the correct B fragment. R12 post-mortem: the per-layer LDS round-trip (not barriers)
// was the serial cost; this deletes it.

typedef __attribute__((ext_vector_type(8))) short bf16x8;
typedef __attribute__((ext_vector_type(4))) float f32x4;

union U4B { uint4 u; bf16x8 b; };

__device__ __forceinline__ unsigned short f2bf(float f) {
  union { float f; unsigned u; } v; v.f = f;
  return (unsigned short)((v.u + 0x7FFFu + ((v.u >> 16) & 1u)) >> 16);  // RNE
}

__device__ __forceinline__ unsigned cvtpk(float lo, float hi) {
  unsigned r;
  asm("v_cvt_pk_bf16_f32 %0, %1, %2" : "=v"(r) : "v"(lo), "v"(hi));
  return r;
}

// K-dim permutation matching the in-register accumulator packing:
// B element position k=(kk,gg,i) holds feature 32*kk + 16*(i>>2) + 4*gg + (i&3).
__host__ __device__ __forceinline__ int kperm(int k) {
  int kk = k >> 5, gg = (k >> 3) & 3, i = k & 7;
  return kk * 32 + (i >> 2) * 16 + gg * 4 + (i & 3);
}

// ---------------- weight prep: bf16 A-operand images in ws ----------------
// shorts: A1c [128j][8k] @0 ; A3e [128j][8k] @1024 ; wn2 cols f32[2][128] @2048 ;
//         be2 f32[128] @2560 ; A2 (K-permuted) @4096 ; A3 (K-permuted) @20480.
__global__ void gn_prep(const float* __restrict__ We1, const float* __restrict__ be1,
                        const float* __restrict__ We2, const float* __restrict__ Wn1,
                        const float* __restrict__ bn1, const float* __restrict__ Wn2,
                        const float* __restrict__ be2,
                        unsigned short* __restrict__ wsA) {
  int t = blockIdx.x * 256 + threadIdx.x;
  if (t < 1024) {                       // A1 compact: k<7 -> We1 rows 10..16 ; k==7 -> be1
    int j = t >> 3, k = t & 7;
    wsA[t] = f2bf((k < 7) ? We1[(10 + k) * 128 + j] : be1[j]);
  } else if (t < 2048) {                // A3ext compact: c0=Wn1r10, c1=Wn1r11, c2=bn1
    int t2 = t - 1024; int j = t2 >> 3, c = t2 & 7;
    float v = (c == 0) ? Wn1[10 * 128 + j] : (c == 1) ? Wn1[11 * 128 + j]
            : (c == 2) ? bn1[j] : 0.0f;
    wsA[t] = f2bf(v);
  } else if (t < 2304) {                // Wn2 columns, f32: [c][j]
    int f = t - 2048; int c = f >> 7, j = f & 127;
    ((float*)(wsA + 2048))[f] = Wn2[j * 2 + c];
  } else if (t < 2432) {                // be2, f32
    int f = t - 2304;
    ((float*)(wsA + 2560))[f] = be2[f];
  } else if (t >= 4096 && t < 20480) {  // A2 = We2^T, K-permuted
    int t2 = t - 4096; int j = t2 >> 7, k = t2 & 127;
    wsA[t] = f2bf(We2[kperm(k) * 128 + j]);
  } else if (t >= 20480 && t < 36864) { // A3 main = Wn1[12:140]^T, K-permuted
    int t2 = t - 20480; int j = t2 >> 7, k = t2 & 127;
    wsA[t] = f2bf(Wn1[(12 + kperm(k)) * 128 + j]);
  }
}

// ---------------- main fused kernel ----------------
#define WTILES 16384  // 262144 rows / 16 rows per wave-tile
#define NWAVES 2048   // grid 512 x 4 waves; 8 tiles per wave

__global__ __launch_bounds__(256) __attribute__((amdgpu_waves_per_eu(2, 2)))
void gn_main(
    const float* __restrict__ x, const float* __restrict__ u,
    const float* __restrict__ nmean, const float* __restrict__ nstd,
    const float* __restrict__ emean, const float* __restrict__ estd,
    const float* __restrict__ bn2,
    const unsigned short* __restrict__ wsA,
    float* __restrict__ out)
{
  __shared__ __align__(16) unsigned short a2T[128 * 128];   // 32KB swizzled A2 table
  __shared__ __align__(16) unsigned short aLDS[2816];       // 5.5KB compact tables

  const int tid  = threadIdx.x;
  const int lane = tid & 63;
  const int wid  = tid >> 6;
  const int c15  = lane & 15;
  const int g    = lane >> 4;    // 0..3
  const int sw15 = (c15 & 7) << 4;

  // ---- build swizzled A2 table + compact tables in LDS (one time) ----
  for (int t = tid; t < 2048; t += 256) {
    int j = t >> 4, c = t & 15;
    uint4 v = *(const uint4*)(wsA + 4096 + j * 128 + c * 8);
    *(uint4*)((char*)a2T + j * 256 + ((c * 16) ^ ((j & 7) << 4))) = v;
  }
  for (int t = tid; t < 1408; t += 256)
    ((unsigned*)aLDS)[t] = ((const unsigned*)wsA)[t];

  // ---- resident A3 fragments: full feature dim, 128 AGPRs ----
  bf16x8 A3f[8][4];
  #pragma unroll
  for (int m = 0; m < 8; ++m)
    #pragma unroll
    for (int kk = 0; kk < 4; ++kk)
      A3f[m][kk] = *(const bf16x8*)(wsA + 20480 + (m * 16 + c15) * 128 + kk * 32 + g * 8);

  const float nm0 = nmean[0], nm1 = nmean[1];
  const float is0 = 1.0f / nstd[0], is1 = 1.0f / nstd[1];
  const float em0 = emean[0], ie0 = 1.0f / estd[0];
  const float cea1 = (0.0f - emean[1]) / estd[1];
  const float cea2 = (0.0f - emean[2]) / estd[2];
  const float bn20 = bn2[0], bn21 = bn2[1];
  const unsigned cpkw = cvtpk(cea2, 1.0f);   // B dword3: [cea2, 1.0]

  // ---- prefetch first tile's x/u ----
  float4 xv; float uv;
  if (g == 0) {
    int b = (blockIdx.x * 4 + wid) * 8 + (c15 >> 1);
    xv = *(const float4*)(x + b * 4);
    uv = u[b];
  }
  __syncthreads();   // tables ready — the only barrier

  for (int wt = blockIdx.x * 4 + wid; wt < WTILES; wt += NWAVES) {
    const int rowbase = wt * 16;

    // opaque LDS offset: stop LICM from hoisting loop-invariant table reads into regs
    unsigned aoff = 0;
    asm volatile("" : "+v"(aoff));
    const char* aB  = (const char*)aLDS + aoff;
    const char* a2B = (const char*)a2T + aoff;

    // ---------- build G1 B-operand in registers ----------
    unsigned pks = 0;
    bf16x8 Bv;
    {
      uint4 bu = (uint4){0u, 0u, 0u, 0u};
      if (g == 0) {                     // only k=0..7 nonzero; g==0 lanes hold them
        float a0 = (xv.x - nm0) * is0;  // node0 theta
        float a1 = (xv.z - nm1) * is1;  // node0 v
        float b0 = (xv.y - nm0) * is0;  // node1 theta
        float b1 = (xv.w - nm1) * is1;  // node1 v
        bool  e  = (c15 & 1);           // row parity = edge index
        float s0 = e ? b0 : a0, s1 = e ? b1 : a1;   // sender  feats
        float r0 = e ? a0 : b0, r1 = e ? a1 : b1;   // receiver feats
        float ea0 = (uv - em0) * ie0;
        bu.x = cvtpk(s0, s1);
        bu.y = cvtpk(r0, r1);
        bu.z = cvtpk(ea0, cea1);
        bu.w = cpkw;
      }
      pks = bu.x;                       // sender feats, reused as G3 node feats
      U4B t; t.u = bu; Bv = t.b;
    }

    // ---------- prefetch next tile's x/u ----------
    {
      int nt = wt + NWAVES;
      if (nt < WTILES && g == 0) {
        int b = nt * 8 + (c15 >> 1);
        xv = *(const float4*)(x + b * 4);
        uv = u[b];
      }
    }

    f32x4 acc[8];

    // ---------- G1: e1 = relu(A1 @ in32), stays in registers ----------
    #pragma unroll
    for (int m = 0; m < 8; ++m) {
      U4B ta; ta.u = *(const uint4*)(aB + (m * 16 + c15) * 16);   // A1 frag
      f32x4 z = (f32x4){0.f, 0.f, 0.f, 0.f};
      acc[m] = __builtin_amdgcn_mfma_f32_16x16x32_bf16(ta.b, Bv, z, 0, 0, 0);
    }
    bf16x8 E1[4];                       // packed e1 = B fragments for G2 (kperm'd image)
    #pragma unroll
    for (int kk = 0; kk < 4; ++kk) {
      f32x4 a0 = acc[2 * kk], a1 = acc[2 * kk + 1];
      uint4 e;
      e.x = cvtpk(fmaxf(a0[0], 0.f), fmaxf(a0[1], 0.f));
      e.y = cvtpk(fmaxf(a0[2], 0.f), fmaxf(a0[3], 0.f));
      e.z = cvtpk(fmaxf(a1[0], 0.f), fmaxf(a1[1], 0.f));
      e.w = cvtpk(fmaxf(a1[2], 0.f), fmaxf(a1[3], 0.f));
      U4B t; t.u = e; E1[kk] = t.b;
    }

    // ---------- G2: e2 = relu(A2 @ e1 + be2); A2 streamed from LDS table ----------
    #pragma unroll
    for (int m = 0; m < 8; ++m)
      acc[m] = *(const f32x4*)(aB + 5120 + (m * 16 + g * 4) * 4);  // be2 C-init
    #pragma unroll
    for (int kk = 0; kk < 4; ++kk)
      #pragma unroll
      for (int m = 0; m < 8; ++m) {
        U4B ta; ta.u = *(const uint4*)(a2B + (m * 16 + c15) * 256 + ((kk * 64 + g * 16) ^ sw15));
        acc[m] = __builtin_amdgcn_mfma_f32_16x16x32_bf16(ta.b, E1[kk], acc[m], 0, 0, 0);
      }

    // ---------- pack e2 + row^1 aggregation swap (lane l <-> l^1) ----------
    bf16x8 E2s[4];
    #pragma unroll
    for (int kk = 0; kk < 4; ++kk) {
      f32x4 a0 = acc[2 * kk], a1 = acc[2 * kk + 1];
      uint4 e;
      e.x = __shfl_xor(cvtpk(fmaxf(a0[0], 0.f), fmaxf(a0[1], 0.f)), 1, 64);
      e.y = __shfl_xor(cvtpk(fmaxf(a0[2], 0.f), fmaxf(a0[3], 0.f)), 1, 64);
      e.z = __shfl_xor(cvtpk(fmaxf(a1[0], 0.f), fmaxf(a1[1], 0.f)), 1, 64);
      e.w = __shfl_xor(cvtpk(fmaxf(a1[2], 0.f), fmaxf(a1[3], 0.f)), 1, 64);
      U4B t; t.u = e; E2s[kk] = t.b;
    }

    // ---------- G3: hdd = relu(A3 @ [e2[r^1]; sender,1]); A3 resident ----------
    #pragma unroll
    for (int m = 0; m < 8; ++m) acc[m] = (f32x4){0.f, 0.f, 0.f, 0.f};
    #pragma unroll
    for (int kk = 0; kk < 4; ++kk)
      #pragma unroll
      for (int m = 0; m < 8; ++m)
        acc[m] = __builtin_amdgcn_mfma_f32_16x16x32_bf16(A3f[m][kk], E2s[kk], acc[m], 0, 0, 0);
    {
      // K-chunk 4: node feats (= sender feats, own row) + const-1 (bn1 column)
      uint4 b4u = (uint4){0u, 0u, 0u, 0u};
      if (g == 0) { b4u.x = pks; b4u.y = 0x00003F80u; }
      U4B t4; t4.u = b4u;
      #pragma unroll
      for (int m = 0; m < 8; ++m) {
        U4B ta; ta.u = *(const uint4*)(aB + 2048 + (m * 16 + c15) * 16);  // A3e frag
        acc[m] = __builtin_amdgcn_mfma_f32_16x16x32_bf16(ta.b, t4.b, acc[m], 0, 0, 0);
      }
    }

    // ---------- G4: delta = Wn2^T @ relu(hdd) + bn2; dot + g-reduce + store ----------
    {
      float p0 = 0.f, p1 = 0.f;
      #pragma unroll
      for (int m = 0; m < 8; ++m) {
        int jo = (m * 16 + g * 4) * 4;                 // byte offset into f32[128]
        f32x4 w0 = *(const f32x4*)(aB + 4096 + jo);    // Wn2 col0
        f32x4 w1 = *(const f32x4*)(aB + 4608 + jo);    // Wn2 col1
        #pragma unroll
        for (int r = 0; r < 4; ++r) {
          float h = fmaxf(acc[m][r], 0.f);
          p0 += h * w0[r];
          p1 += h * w1[r];
        }
      }
      p0 += __shfl_xor(p0, 16, 64); p0 += __shfl_xor(p0, 32, 64);
      p1 += __shfl_xor(p1, 16, 64); p1 += __shfl_xor(p1, 32, 64);
      if (g == 0) {                    // lane holds delta c0,c1 for row rowbase+c15
        int gr = rowbase + c15;
        int bidx = gr >> 1, k = gr & 1;
        out[bidx * 4 + k]     = x[bidx * 4 + k]     + p0 + bn20;
        out[bidx * 4 + k + 2] = x[bidx * 4 + k + 2] + p1 + bn21;
      }
    }
    // no barrier: everything per-wave in registers; LDS tables are read-only.
  }
}

extern "C" void kernel_launch(void* const* d_in, const int* in_sizes, int n_in,
                              void* d_out, int out_size, void* d_ws, size_t ws_size,
                              hipStream_t stream) {
  const float* x   = (const float*)d_in[0];
  const float* u   = (const float*)d_in[1];
  const float* nm  = (const float*)d_in[2];
  const float* ns  = (const float*)d_in[3];
  const float* em  = (const float*)d_in[4];
  const float* es  = (const float*)d_in[5];
  const float* We1 = (const float*)d_in[6];
  const float* be1 = (const float*)d_in[7];
  const float* We2 = (const float*)d_in[8];
  const float* be2 = (const float*)d_in[9];
  const float* Wn1 = (const float*)d_in[10];
  const float* bn1 = (const float*)d_in[11];
  const float* Wn2 = (const float*)d_in[12];
  const float* bn2 = (const float*)d_in[13];
  unsigned short* wsA = (unsigned short*)d_ws;   // needs 73728 bytes
  float* out = (float*)d_out;

  gn_prep<<<144, 256, 0, stream>>>(We1, be1, We2, Wn1, bn1, Wn2, be2, wsA);
  gn_main<<<512, 256, 0, stream>>>(x, u, nm, ns, em, es, bn2, wsA, out);
}